// Round 4
// baseline (70.410 us; speedup 1.0000x reference)
//
#include <hip/hip_runtime.h>

// SelfAttention2d, B=8 C=256 H=W=64 (N=4096), Ck=32, softmax dead code.
// out = gamma * (v q^T k) + x, reassociated:
//   Qt = X^T Wq^T + 1 bq^T      (N x 32, per-tile, LDS only)
//   Kt_t = X^T Wk^T             (N x 32, bf16, ws; bk folded into h)
//   T  = X Qt                   (256 x 32) n-chunked partials -> ws
//   qsum = Qt^T 1               (32)
//   P  = Wv T + bv qsum^T       (256 x 32), h = P bk  (j-split over 2 blocks)
//   out = gamma * (P Kt + h 1^T) + x   [back: pure streaming, no LDS]

constexpr int NB = 8;
constexpr int NC = 256;
constexpr int NK = 32;     // C/8
constexpr int NN = 4096;   // H*W

typedef float  f32x4  __attribute__((ext_vector_type(4)));
typedef __bf16 bf16x4 __attribute__((ext_vector_type(4)));
typedef __bf16 bf16x8 __attribute__((ext_vector_type(8)));

__device__ __forceinline__ bf16x8 load_bf8(const float* __restrict__ p) {
  f32x4 a = *(const f32x4*)p;
  f32x4 b = *(const f32x4*)(p + 4);
  bf16x8 r;
  r[0] = (__bf16)a[0]; r[1] = (__bf16)a[1]; r[2] = (__bf16)a[2]; r[3] = (__bf16)a[3];
  r[4] = (__bf16)b[0]; r[5] = (__bf16)b[1]; r[6] = (__bf16)b[2]; r[7] = (__bf16)b[3];
  return r;
}

// ---------------- front: Qt/Kt per 64-n subtile; T partials; qsum partials ----
// grid = NB*(64/S) blocks, 512 threads (8 waves): waves 0-3 Qt, waves 4-7 Kt.
// S = subtiles per block (1 when ws allows 64-chunk Tpart, else 2).
template <int S>
__global__ __launch_bounds__(512) void k_front(
    const float* __restrict__ x, const float* __restrict__ Wq,
    const float* __restrict__ bq, const float* __restrict__ Wk,
    __bf16* __restrict__ Tpart, __bf16* __restrict__ Kt_t,
    float* __restrict__ qsum_part) {
  constexpr int CHUNKS = 64 / S;
  __shared__ __bf16 ldsT[64][264];   // x-subtile transposed [n][c]
  __shared__ __bf16 ldsQt[32][72];   // Q^T subtile [j][n]
  __shared__ __bf16 ldsKt[32][72];   // K^T subtile [j][n]
  __shared__ float  ldsQs[4][32];
  int bid = blockIdx.x;
  int b = bid / CHUNKS, chunk = bid - b * CHUNKS;
  int t = threadIdx.x;
  int lane = t & 63, w = t >> 6, lr = lane & 15, lg = lane >> 4;
  const float* xb = x + (size_t)b * NC * NN;
  const bool isQ = (w < 4);
  int wh = w & 3;
  const float* Wrow = isQ ? Wq : Wk;
  float bq0 = bq[lr], bq1 = bq[16 + lr];
  float qs0 = 0.f, qs1 = 0.f;
  f32x4 accT[2][2] = {};

  for (int s = 0; s < S; ++s) {
    int nsub = (chunk * S + s) * 64;
    {  // stage x[0:256][nsub:nsub+64] -> ldsT[n][c] bf16 (4x4 register transpose)
      int c0 = (t & 63) * 4, nq = (t >> 6) * 4;
#pragma unroll
      for (int p = 0; p < 2; ++p) {
        int n = p * 32 + nq;
        f32x4 v0 = *(const f32x4*)(xb + (size_t)(c0 + 0) * NN + nsub + n);
        f32x4 v1 = *(const f32x4*)(xb + (size_t)(c0 + 1) * NN + nsub + n);
        f32x4 v2 = *(const f32x4*)(xb + (size_t)(c0 + 2) * NN + nsub + n);
        f32x4 v3 = *(const f32x4*)(xb + (size_t)(c0 + 3) * NN + nsub + n);
#pragma unroll
        for (int i = 0; i < 4; ++i) {
          bf16x4 wv = {(__bf16)v0[i], (__bf16)v1[i], (__bf16)v2[i], (__bf16)v3[i]};
          *(bf16x4*)&ldsT[n + i][c0] = wv;
        }
      }
    }
    __syncthreads();
    // Qt waves compute Qt(64x32), Kt waves compute Kt(64x32); shared ldsT rows.
    f32x4 a0 = {}, a1 = {};
#pragma unroll
    for (int ks = 0; ks < 8; ++ks) {
      bf16x8 af = *(const bf16x8*)&ldsT[wh * 16 + lr][ks * 32 + lg * 8];
      bf16x8 w0 = load_bf8(Wrow + (size_t)lr * NC + ks * 32 + lg * 8);
      bf16x8 w1 = load_bf8(Wrow + (size_t)(16 + lr) * NC + ks * 32 + lg * 8);
      a0 = __builtin_amdgcn_mfma_f32_16x16x32_bf16(af, w0, a0, 0, 0, 0);
      a1 = __builtin_amdgcn_mfma_f32_16x16x32_bf16(af, w1, a1, 0, 0, 0);
    }
    if (isQ) {
#pragma unroll
      for (int r = 0; r < 4; ++r) { a0[r] += bq0; a1[r] += bq1; }
      qs0 += a0[0] + a0[1] + a0[2] + a0[3];
      qs1 += a1[0] + a1[1] + a1[2] + a1[3];
      bf16x4 p0 = {(__bf16)a0[0], (__bf16)a0[1], (__bf16)a0[2], (__bf16)a0[3]};
      bf16x4 p1 = {(__bf16)a1[0], (__bf16)a1[1], (__bf16)a1[2], (__bf16)a1[3]};
      *(bf16x4*)&ldsQt[lr][wh * 16 + lg * 4] = p0;
      *(bf16x4*)&ldsQt[16 + lr][wh * 16 + lg * 4] = p1;
    } else {
      bf16x4 p0 = {(__bf16)a0[0], (__bf16)a0[1], (__bf16)a0[2], (__bf16)a0[3]};
      bf16x4 p1 = {(__bf16)a1[0], (__bf16)a1[1], (__bf16)a1[2], (__bf16)a1[3]};
      *(bf16x4*)&ldsKt[lr][wh * 16 + lg * 4] = p0;
      *(bf16x4*)&ldsKt[16 + lr][wh * 16 + lg * 4] = p1;
    }
    __syncthreads();
    // T(256x32) += X Qt : A = x rows from global (L1/L2-hot), B = ldsQt rows.
    // Wave w owns c-rows [w*32, w*32+32).
#pragma unroll
    for (int ks2 = 0; ks2 < 2; ++ks2) {
      bf16x8 bf0 = *(const bf16x8*)&ldsQt[lr][ks2 * 32 + lg * 8];
      bf16x8 bf1 = *(const bf16x8*)&ldsQt[16 + lr][ks2 * 32 + lg * 8];
#pragma unroll
      for (int mt = 0; mt < 2; ++mt) {
        int c = w * 32 + mt * 16 + lr;
        bf16x8 af = load_bf8(xb + (size_t)c * NN + nsub + ks2 * 32 + lg * 8);
        accT[mt][0] = __builtin_amdgcn_mfma_f32_16x16x32_bf16(af, bf0, accT[mt][0], 0, 0, 0);
        accT[mt][1] = __builtin_amdgcn_mfma_f32_16x16x32_bf16(af, bf1, accT[mt][1], 0, 0, 0);
      }
    }
    // Kt coalesced store: 512 threads cover 64 rows x 32 j (8B each)
    {
      int nloc = t >> 3, j0 = (t & 7) * 4;
      bf16x4 pk = {ldsKt[j0 + 0][nloc], ldsKt[j0 + 1][nloc],
                   ldsKt[j0 + 2][nloc], ldsKt[j0 + 3][nloc]};
      *(bf16x4*)&Kt_t[((size_t)b * NN + nsub + nloc) * NK + j0] = pk;
    }
  }
  // qsum partial (Qt waves only hold data)
  if (isQ) {
    qs0 += __shfl_xor(qs0, 16); qs0 += __shfl_xor(qs0, 32);
    qs1 += __shfl_xor(qs1, 16); qs1 += __shfl_xor(qs1, 32);
    if (lane < 16) { ldsQs[wh][lane] = qs0; ldsQs[wh][16 + lane] = qs1; }
  }
  __syncthreads();
  if (t < 32)
    qsum_part[(size_t)(chunk * NB + b) * NK + t] =
        ldsQs[0][t] + ldsQs[1][t] + ldsQs[2][t] + ldsQs[3][t];
  // Tpart[chunk][b][j][c] bf16
  __bf16* Tp = Tpart + (size_t)(chunk * NB + b) * NC * NK;
#pragma unroll
  for (int mt = 0; mt < 2; ++mt)
#pragma unroll
    for (int jf = 0; jf < 2; ++jf) {
      bf16x4 pk = {(__bf16)accT[mt][jf][0], (__bf16)accT[mt][jf][1],
                   (__bf16)accT[mt][jf][2], (__bf16)accT[mt][jf][3]};
      *(bf16x4*)&Tp[(jf * 16 + lr) * NC + w * 32 + mt * 16 + lg * 4] = pk;
    }
}

// ---------------- mid: reduce Tpart (j-half) -> T; P-half; h-half -------------
// grid = NB*2 (j-split), 256 threads
template <int CHUNKS>
__global__ __launch_bounds__(256) void k_mid(
    const __bf16* __restrict__ Tpart, const float* __restrict__ qsum_part,
    const float* __restrict__ Wv, const float* __restrict__ bv,
    const float* __restrict__ bk, __bf16* __restrict__ P,
    float* __restrict__ h2) {
  __shared__ __bf16 shTt[16][264];  // T^T half [j][c]
  __shared__ float shQsum[16];
  int bid = blockIdx.x;
  int b = bid >> 1, jg = bid & 1;
  int t = threadIdx.x;
  if (t < 16) {
    float s = 0.f;
#pragma unroll 8
    for (int ch = 0; ch < CHUNKS; ++ch)
      s += qsum_part[(size_t)(ch * NB + b) * NK + jg * 16 + t];
    shQsum[t] = s;
  }
  // coalesced partial-sum: half-tile is 16j x 256c = 4096 elems
  float acc[4][4] = {};
#pragma unroll 4
  for (int ch = 0; ch < CHUNKS; ++ch) {
    const __bf16* base =
        Tpart + (size_t)(ch * NB + b) * NC * NK + (size_t)jg * 16 * NC;
#pragma unroll
    for (int rep = 0; rep < 4; ++rep) {
      bf16x4 v = *(const bf16x4*)(base + rep * 1024 + t * 4);
#pragma unroll
      for (int i = 0; i < 4; ++i) acc[rep][i] += (float)v[i];
    }
  }
  {
    int jrow = t >> 6, c0 = (t & 63) * 4;
#pragma unroll
    for (int rep = 0; rep < 4; ++rep) {
      bf16x4 pk = {(__bf16)acc[rep][0], (__bf16)acc[rep][1],
                   (__bf16)acc[rep][2], (__bf16)acc[rep][3]};
      *(bf16x4*)&shTt[rep * 4 + jrow][c0] = pk;
    }
  }
  __syncthreads();
  // P[:, jg*16..+16] = Wv T_half + bv qsum_half^T ; h-half = P_half bk_half
  int lane = t & 63, w = t >> 6, lr = lane & 15, lg = lane >> 4;
  float bkj = bk[jg * 16 + lr];
  f32x4 accP[4] = {};
#pragma unroll
  for (int ks = 0; ks < 8; ++ks) {
    bf16x8 b0 = *(const bf16x8*)&shTt[lr][ks * 32 + lg * 8];
#pragma unroll
    for (int mt = 0; mt < 4; ++mt) {
      int c = w * 64 + mt * 16 + lr;
      bf16x8 af = load_bf8(Wv + (size_t)c * NC + ks * 32 + lg * 8);
      accP[mt] = __builtin_amdgcn_mfma_f32_16x16x32_bf16(af, b0, accP[mt], 0, 0, 0);
    }
  }
  float qs = shQsum[lr];
#pragma unroll
  for (int mt = 0; mt < 4; ++mt) {
    float hacc[4];
#pragma unroll
    for (int r = 0; r < 4; ++r) {
      int c = w * 64 + mt * 16 + lg * 4 + r;
      float val = accP[mt][r] + bv[c] * qs;
      P[((size_t)b * NC + c) * NK + jg * 16 + lr] = (__bf16)val;
      hacc[r] = val * bkj;
    }
#pragma unroll
    for (int r = 0; r < 4; ++r) {
      float v = hacc[r];
      v += __shfl_xor(v, 1); v += __shfl_xor(v, 2);
      v += __shfl_xor(v, 4); v += __shfl_xor(v, 8);
      if (lr == 0)
        h2[((size_t)b * 2 + jg) * NC + w * 64 + mt * 16 + lg * 4 + r] = v;
    }
  }
}

// ---------------- back: out = gamma*(P Kt + h 1^T) + x -----------------------
// D[n][c] orientation: A = Kt_t[n][j] (global, contiguous), B = P[c][j] rows.
// grid = NB*64 (n-tiles of 64), 256 threads (4 waves), NO LDS, NO syncs.
__global__ __launch_bounds__(256) void k_back(
    const float* __restrict__ x, const __bf16* __restrict__ Kt_t,
    const __bf16* __restrict__ P, const float* __restrict__ h2,
    const float* __restrict__ gamma, float* __restrict__ out) {
  int bid = blockIdx.x;
  int b = bid >> 6, n0 = (bid & 63) * 64;
  int t = threadIdx.x;
  int lane = t & 63, w = t >> 6, lr = lane & 15, lg = lane >> 4;

  bf16x8 af = *(const bf16x8*)&Kt_t[((size_t)b * NN + n0 + w * 16 + lr) * NK + lg * 8];
  const __bf16* Pb = P + (size_t)b * NC * NK;
  f32x4 acc[16];
#pragma unroll
  for (int ft = 0; ft < 16; ++ft) {
    bf16x8 bfr = *(const bf16x8*)&Pb[(size_t)(ft * 16 + lr) * NK + lg * 8];
    f32x4 z = {0.f, 0.f, 0.f, 0.f};
    acc[ft] = __builtin_amdgcn_mfma_f32_16x16x32_bf16(af, bfr, z, 0, 0, 0);
  }
  float g = gamma[0];
  const float* h0 = h2 + (size_t)b * 2 * NC;
#pragma unroll
  for (int ft = 0; ft < 16; ++ft) {
    int c = ft * 16 + lr;
    float hc = h0[c] + h0[NC + c];
    size_t idx = ((size_t)b * NC + c) * NN + n0 + w * 16 + lg * 4;
    f32x4 xv = *(const f32x4*)&x[idx];
    f32x4 o;
#pragma unroll
    for (int r = 0; r < 4; ++r) o[r] = g * (acc[ft][r] + hc) + xv[r];
    *(f32x4*)&out[idx] = o;
  }
}

extern "C" void kernel_launch(void* const* d_in, const int* in_sizes, int n_in,
                              void* d_out, int out_size, void* d_ws, size_t ws_size,
                              hipStream_t stream) {
  (void)in_sizes; (void)n_in; (void)out_size;
  const float* x     = (const float*)d_in[0];
  const float* Wk    = (const float*)d_in[1];
  const float* bk    = (const float*)d_in[2];
  const float* Wq    = (const float*)d_in[3];
  const float* bq    = (const float*)d_in[4];
  const float* Wv    = (const float*)d_in[5];
  const float* bv    = (const float*)d_in[6];
  const float* gamma = (const float*)d_in[7];
  float* out = (float*)d_out;

  const size_t ktB = (size_t)NB * NN * NK * 2;   // 2 MB
  const size_t pB  = (size_t)NB * NC * NK * 2;   // 128 KB
  const size_t hB  = (size_t)NB * 2 * NC * 4;    // 16 KB

  auto run = [&](auto schunks, __bf16* Tpart, __bf16* Kt_t, float* qsum_part,
                 __bf16* P, float* h2) {
    constexpr int CH = decltype(schunks)::value;
    constexpr int S = 64 / CH;
    k_front<S><<<NB * CH, 512, 0, stream>>>(x, Wq, bq, Wk, Tpart, Kt_t, qsum_part);
    k_mid<CH><<<NB * 2, 256, 0, stream>>>(Tpart, qsum_part, Wv, bv, bk, P, h2);
    k_back<<<NB * 64, 256, 0, stream>>>(x, Kt_t, P, h2, gamma, out);
  };

  char* wsb = (char*)d_ws;
  const size_t tp64 = (size_t)64 * NB * NC * NK * 2;  // 8 MB
  const size_t qs64 = (size_t)64 * NB * NK * 4;       // 64 KB
  if (ws_size >= tp64 + ktB + qs64 + pB + hB) {
    __bf16* Tpart = (__bf16*)wsb;
    __bf16* Kt_t  = (__bf16*)(wsb + tp64);
    float*  qsp   = (float*)(wsb + tp64 + ktB);
    __bf16* P     = (__bf16*)(wsb + tp64 + ktB + qs64);
    float*  h2    = (float*)(wsb + tp64 + ktB + qs64 + pB);
    run(std::integral_constant<int, 64>{}, Tpart, Kt_t, qsp, P, h2);
  } else {
    const size_t tp32 = (size_t)32 * NB * NC * NK * 2;  // 4 MB
    const size_t qs32 = (size_t)32 * NB * NK * 4;       // 32 KB
    __bf16* Tpart = (__bf16*)wsb;
    __bf16* Kt_t  = (__bf16*)(wsb + tp32);
    float*  qsp   = (float*)(wsb + tp32 + ktB);
    __bf16* P     = (__bf16*)(wsb + tp32 + ktB + qs32);
    float*  h2    = (float*)(wsb + tp32 + ktB + qs32 + pB);
    run(std::integral_constant<int, 32>{}, Tpart, Kt_t, qsp, P, h2);
  }
}

// Round 5
// 60.115 us; speedup vs baseline: 1.1713x; 1.1713x over previous
//
#include <hip/hip_runtime.h>

// SelfAttention2d, B=8 C=256 H=W=64 (N=4096), Ck=32, softmax dead code.
// out = gamma * (v q^T k) + x, reassociated:
//   Qt = X^T Wq^T + 1 bq^T      (N x 32, per-tile, LDS only)
//   Kt_t = X^T Wk^T             (N x 32, bf16, ws; bk folded into h)
//   T  = X Qt                   (256 x 32) n-chunked partials -> ws
//   qsum = Qt^T 1               (32)
//   P  = Wv T + bv qsum^T       (256 x 32), h = P bk  (j-split over 2 blocks)
//   out = gamma * (P Kt + h 1^T) + x   [back: pure streaming, no LDS]
// Mid phase split: wide k_reduce (64 blocks, in-place into Tpart ch=0) +
// tiny k_pgemm (16 blocks) — fixes the 8-CU single-block stream bottleneck.

constexpr int NB = 8;
constexpr int NC = 256;
constexpr int NK = 32;     // C/8
constexpr int NN = 4096;   // H*W
constexpr int NCHUNK = 32; // front n-chunks (128 n each, 2 subtiles of 64)

typedef float  f32x4  __attribute__((ext_vector_type(4)));
typedef __bf16 bf16x4 __attribute__((ext_vector_type(4)));
typedef __bf16 bf16x8 __attribute__((ext_vector_type(8)));

__device__ __forceinline__ bf16x8 load_bf8(const float* __restrict__ p) {
  f32x4 a = *(const f32x4*)p;
  f32x4 b = *(const f32x4*)(p + 4);
  bf16x8 r;
  r[0] = (__bf16)a[0]; r[1] = (__bf16)a[1]; r[2] = (__bf16)a[2]; r[3] = (__bf16)a[3];
  r[4] = (__bf16)b[0]; r[5] = (__bf16)b[1]; r[6] = (__bf16)b[2]; r[7] = (__bf16)b[3];
  return r;
}

// ---------------- front: Qt/Kt per subtile; T partials; qsum partials ---------
// grid = NB*NCHUNK (256 blocks), 256 threads (4 waves), 2 serial 64-n subtiles.
__global__ __launch_bounds__(256) void k_front(
    const float* __restrict__ x, const float* __restrict__ Wq,
    const float* __restrict__ bq, const float* __restrict__ Wk,
    __bf16* __restrict__ Tpart, __bf16* __restrict__ Kt_t,
    float* __restrict__ qsum_part) {
  __shared__ __bf16 ldsT[64][264];   // x-subtile transposed [n][c]
  __shared__ __bf16 ldsQt[32][72];   // Q^T subtile [j][n]
  __shared__ __bf16 ldsKt[32][72];   // K^T subtile [j][n]
  __shared__ float  ldsQs[4][32];
  int bid = blockIdx.x;
  int b = bid >> 5, chunk = bid & 31;
  int t = threadIdx.x;
  int lane = t & 63, w = t >> 6, lr = lane & 15, lg = lane >> 4;
  const float* xb = x + (size_t)b * NC * NN;
  float bq0 = bq[lr], bq1 = bq[16 + lr];
  float qs0 = 0.f, qs1 = 0.f;
  f32x4 accT[4][2] = {};

  for (int s = 0; s < 2; ++s) {
    int nsub = chunk * 128 + s * 64;
    {  // stage x[0:256][nsub:nsub+64] -> ldsT[n][c] bf16 (4x4 register transpose)
      int c0 = (t & 63) * 4, nq = (t >> 6) * 4;
#pragma unroll
      for (int p = 0; p < 4; ++p) {
        int n = p * 16 + nq;
        f32x4 v0 = *(const f32x4*)(xb + (size_t)(c0 + 0) * NN + nsub + n);
        f32x4 v1 = *(const f32x4*)(xb + (size_t)(c0 + 1) * NN + nsub + n);
        f32x4 v2 = *(const f32x4*)(xb + (size_t)(c0 + 2) * NN + nsub + n);
        f32x4 v3 = *(const f32x4*)(xb + (size_t)(c0 + 3) * NN + nsub + n);
#pragma unroll
        for (int i = 0; i < 4; ++i) {
          bf16x4 wv = {(__bf16)v0[i], (__bf16)v1[i], (__bf16)v2[i], (__bf16)v3[i]};
          *(bf16x4*)&ldsT[n + i][c0] = wv;
        }
      }
    }
    __syncthreads();
    // Qt(64x32) and Kt(64x32): A = x^T from ldsT (shared), B = Wq/Wk rows
    f32x4 aq[2] = {}, ak[2] = {};
#pragma unroll
    for (int ks = 0; ks < 8; ++ks) {
      bf16x8 af = *(const bf16x8*)&ldsT[w * 16 + lr][ks * 32 + lg * 8];
      bf16x8 q0 = load_bf8(Wq + (size_t)lr * NC + ks * 32 + lg * 8);
      bf16x8 q1 = load_bf8(Wq + (size_t)(16 + lr) * NC + ks * 32 + lg * 8);
      bf16x8 k0 = load_bf8(Wk + (size_t)lr * NC + ks * 32 + lg * 8);
      bf16x8 k1 = load_bf8(Wk + (size_t)(16 + lr) * NC + ks * 32 + lg * 8);
      aq[0] = __builtin_amdgcn_mfma_f32_16x16x32_bf16(af, q0, aq[0], 0, 0, 0);
      aq[1] = __builtin_amdgcn_mfma_f32_16x16x32_bf16(af, q1, aq[1], 0, 0, 0);
      ak[0] = __builtin_amdgcn_mfma_f32_16x16x32_bf16(af, k0, ak[0], 0, 0, 0);
      ak[1] = __builtin_amdgcn_mfma_f32_16x16x32_bf16(af, k1, ak[1], 0, 0, 0);
    }
#pragma unroll
    for (int r = 0; r < 4; ++r) { aq[0][r] += bq0; aq[1][r] += bq1; }
    qs0 += aq[0][0] + aq[0][1] + aq[0][2] + aq[0][3];
    qs1 += aq[1][0] + aq[1][1] + aq[1][2] + aq[1][3];
    // Qt / Kt -> LDS [j][n]
    {
      bf16x4 p0 = {(__bf16)aq[0][0], (__bf16)aq[0][1], (__bf16)aq[0][2], (__bf16)aq[0][3]};
      bf16x4 p1 = {(__bf16)aq[1][0], (__bf16)aq[1][1], (__bf16)aq[1][2], (__bf16)aq[1][3]};
      *(bf16x4*)&ldsQt[lr][w * 16 + lg * 4] = p0;
      *(bf16x4*)&ldsQt[16 + lr][w * 16 + lg * 4] = p1;
      bf16x4 k0p = {(__bf16)ak[0][0], (__bf16)ak[0][1], (__bf16)ak[0][2], (__bf16)ak[0][3]};
      bf16x4 k1p = {(__bf16)ak[1][0], (__bf16)ak[1][1], (__bf16)ak[1][2], (__bf16)ak[1][3]};
      *(bf16x4*)&ldsKt[lr][w * 16 + lg * 4] = k0p;
      *(bf16x4*)&ldsKt[16 + lr][w * 16 + lg * 4] = k1p;
    }
    __syncthreads();
    // Kt coalesced store: thread t covers (nloc = t>>2, 8 j) -> 16 B store
    {
      int nloc = t >> 2, j0 = (t & 3) * 8;
      bf16x8 pk;
#pragma unroll
      for (int i = 0; i < 8; ++i) pk[i] = ldsKt[j0 + i][nloc];
      *(bf16x8*)&Kt_t[((size_t)b * NN + nsub + nloc) * NK + j0] = pk;
    }
    // T(256x32) += X Qt : A = x rows from global (L1/L2-hot), B = ldsQt rows
#pragma unroll
    for (int ks2 = 0; ks2 < 2; ++ks2) {
      bf16x8 bf0 = *(const bf16x8*)&ldsQt[lr][ks2 * 32 + lg * 8];
      bf16x8 bf1 = *(const bf16x8*)&ldsQt[16 + lr][ks2 * 32 + lg * 8];
#pragma unroll
      for (int mt = 0; mt < 4; ++mt) {
        int c = w * 64 + mt * 16 + lr;
        bf16x8 af = load_bf8(xb + (size_t)c * NN + nsub + ks2 * 32 + lg * 8);
        accT[mt][0] = __builtin_amdgcn_mfma_f32_16x16x32_bf16(af, bf0, accT[mt][0], 0, 0, 0);
        accT[mt][1] = __builtin_amdgcn_mfma_f32_16x16x32_bf16(af, bf1, accT[mt][1], 0, 0, 0);
      }
    }
  }
  // qsum partial
  qs0 += __shfl_xor(qs0, 16); qs0 += __shfl_xor(qs0, 32);
  qs1 += __shfl_xor(qs1, 16); qs1 += __shfl_xor(qs1, 32);
  if (lane < 16) { ldsQs[w][lane] = qs0; ldsQs[w][16 + lane] = qs1; }
  __syncthreads();
  if (t < 32)
    qsum_part[(size_t)(chunk * NB + b) * NK + t] =
        ldsQs[0][t] + ldsQs[1][t] + ldsQs[2][t] + ldsQs[3][t];
  // Tpart[chunk][b][j][c] bf16 (D rows c are lane-consecutive -> bf16x4 packs)
  __bf16* Tp = Tpart + (size_t)(chunk * NB + b) * NC * NK;
#pragma unroll
  for (int mt = 0; mt < 4; ++mt)
#pragma unroll
    for (int jf = 0; jf < 2; ++jf) {
      bf16x4 pk = {(__bf16)accT[mt][jf][0], (__bf16)accT[mt][jf][1],
                   (__bf16)accT[mt][jf][2], (__bf16)accT[mt][jf][3]};
      *(bf16x4*)&Tp[(jf * 16 + lr) * NC + w * 64 + mt * 16 + lg * 4] = pk;
    }
}

// ---------------- reduce: T = sum_ch Tpart[ch], in-place into Tpart[ch=0] -----
// grid = NB*8 (64 blocks), 256 threads. Block (b, slice of 4 j-rows).
// Each block's output region is a subset of its own input region (ch=0, same
// (b,j,c) range), disjoint across blocks -> no cross-block hazard; front fully
// rewrites Tpart each launch -> deterministic across replays.
__global__ __launch_bounds__(256) void k_reduce(__bf16* __restrict__ Tpart) {
  int bid = blockIdx.x;
  int b = bid >> 3, slice = bid & 7;
  int t = threadIdx.x;
  int jo = t >> 6, c0 = (t & 63) * 4;
  const size_t chstride = (size_t)NB * NK * NC;
  size_t idx = ((size_t)b * NK + slice * 4 + jo) * NC + c0;
  float acc[4] = {};
#pragma unroll 8
  for (int ch = 0; ch < NCHUNK; ++ch) {
    bf16x4 v = *(const bf16x4*)&Tpart[ch * chstride + idx];
#pragma unroll
    for (int i = 0; i < 4; ++i) acc[i] += (float)v[i];
  }
  bf16x4 o = {(__bf16)acc[0], (__bf16)acc[1], (__bf16)acc[2], (__bf16)acc[3]};
  *(bf16x4*)&Tpart[idx] = o;
}

// ---------------- pgemm: P-half = Wv T_half + bv qsum^T ; h-half = P bk -------
// grid = NB*2 (j-split, 16 blocks), 256 threads
__global__ __launch_bounds__(256) void k_pgemm(
    const __bf16* __restrict__ T, const float* __restrict__ qsum_part,
    const float* __restrict__ Wv, const float* __restrict__ bv,
    const float* __restrict__ bk, __bf16* __restrict__ P,
    float* __restrict__ h2) {
  __shared__ __bf16 shTt[16][264];  // T^T half [j][c]
  __shared__ float shQsum[16];
  int bid = blockIdx.x;
  int b = bid >> 1, jg = bid & 1;
  int t = threadIdx.x;
  if (t < 16) {
    float s = 0.f;
#pragma unroll 8
    for (int ch = 0; ch < NCHUNK; ++ch)
      s += qsum_part[(size_t)(ch * NB + b) * NK + jg * 16 + t];
    shQsum[t] = s;
  }
  {  // copy reduced T half (16j x 256c bf16 = 8 KB) into LDS
    int j = t >> 5, c0 = (t & 31) * 8;
    bf16x8 v = *(const bf16x8*)&T[((size_t)b * NK + jg * 16 + j) * NC + c0];
    *(bf16x8*)&shTt[j][c0] = v;
  }
  __syncthreads();
  int lane = t & 63, w = t >> 6, lr = lane & 15, lg = lane >> 4;
  float bkj = bk[jg * 16 + lr];
  f32x4 accP[4] = {};
#pragma unroll
  for (int ks = 0; ks < 8; ++ks) {
    bf16x8 b0 = *(const bf16x8*)&shTt[lr][ks * 32 + lg * 8];
#pragma unroll
    for (int mt = 0; mt < 4; ++mt) {
      int c = w * 64 + mt * 16 + lr;
      bf16x8 af = load_bf8(Wv + (size_t)c * NC + ks * 32 + lg * 8);
      accP[mt] = __builtin_amdgcn_mfma_f32_16x16x32_bf16(af, b0, accP[mt], 0, 0, 0);
    }
  }
  float qs = shQsum[lr];
#pragma unroll
  for (int mt = 0; mt < 4; ++mt) {
    float hacc[4];
#pragma unroll
    for (int r = 0; r < 4; ++r) {
      int c = w * 64 + mt * 16 + lg * 4 + r;
      float val = accP[mt][r] + bv[c] * qs;
      P[((size_t)b * NC + c) * NK + jg * 16 + lr] = (__bf16)val;
      hacc[r] = val * bkj;
    }
#pragma unroll
    for (int r = 0; r < 4; ++r) {
      float v = hacc[r];
      v += __shfl_xor(v, 1); v += __shfl_xor(v, 2);
      v += __shfl_xor(v, 4); v += __shfl_xor(v, 8);
      if (lr == 0)
        h2[((size_t)b * 2 + jg) * NC + w * 64 + mt * 16 + lg * 4 + r] = v;
    }
  }
}

// ---------------- back: out = gamma*(P Kt + h 1^T) + x -----------------------
// D[n][c] orientation: A = Kt_t[n][j] (global, contiguous), B = P[c][j] rows.
// grid = NB*64 (n-tiles of 64), 256 threads (4 waves), NO LDS, NO syncs.
__global__ __launch_bounds__(256) void k_back(
    const float* __restrict__ x, const __bf16* __restrict__ Kt_t,
    const __bf16* __restrict__ P, const float* __restrict__ h2,
    const float* __restrict__ gamma, float* __restrict__ out) {
  int bid = blockIdx.x;
  int b = bid >> 6, n0 = (bid & 63) * 64;
  int t = threadIdx.x;
  int lane = t & 63, w = t >> 6, lr = lane & 15, lg = lane >> 4;

  bf16x8 af = *(const bf16x8*)&Kt_t[((size_t)b * NN + n0 + w * 16 + lr) * NK + lg * 8];
  const __bf16* Pb = P + (size_t)b * NC * NK;
  f32x4 acc[16];
#pragma unroll
  for (int ft = 0; ft < 16; ++ft) {
    bf16x8 bfr = *(const bf16x8*)&Pb[(size_t)(ft * 16 + lr) * NK + lg * 8];
    f32x4 z = {0.f, 0.f, 0.f, 0.f};
    acc[ft] = __builtin_amdgcn_mfma_f32_16x16x32_bf16(af, bfr, z, 0, 0, 0);
  }
  float g = gamma[0];
  const float* h0 = h2 + (size_t)b * 2 * NC;
#pragma unroll
  for (int ft = 0; ft < 16; ++ft) {
    int c = ft * 16 + lr;
    float hc = h0[c] + h0[NC + c];
    size_t idx = ((size_t)b * NC + c) * NN + n0 + w * 16 + lg * 4;
    f32x4 xv = *(const f32x4*)&x[idx];
    f32x4 o;
#pragma unroll
    for (int r = 0; r < 4; ++r) o[r] = g * (acc[ft][r] + hc) + xv[r];
    *(f32x4*)&out[idx] = o;
  }
}

extern "C" void kernel_launch(void* const* d_in, const int* in_sizes, int n_in,
                              void* d_out, int out_size, void* d_ws, size_t ws_size,
                              hipStream_t stream) {
  (void)in_sizes; (void)n_in; (void)out_size; (void)ws_size;
  const float* x     = (const float*)d_in[0];
  const float* Wk    = (const float*)d_in[1];
  const float* bk    = (const float*)d_in[2];
  const float* Wq    = (const float*)d_in[3];
  const float* bq    = (const float*)d_in[4];
  const float* Wv    = (const float*)d_in[5];
  const float* bv    = (const float*)d_in[6];
  const float* gamma = (const float*)d_in[7];
  float* out = (float*)d_out;

  char* wsb = (char*)d_ws;
  const size_t tpB = (size_t)NCHUNK * NB * NC * NK * 2;  // 4 MB
  const size_t ktB = (size_t)NB * NN * NK * 2;           // 2 MB
  const size_t qsB = (size_t)NCHUNK * NB * NK * 4;       // 32 KB
  const size_t pB  = (size_t)NB * NC * NK * 2;           // 128 KB
  __bf16* Tpart = (__bf16*)wsb;
  __bf16* Kt_t  = (__bf16*)(wsb + tpB);
  float*  qsp   = (float*)(wsb + tpB + ktB);
  __bf16* P     = (__bf16*)(wsb + tpB + ktB + qsB);
  float*  h2    = (float*)(wsb + tpB + ktB + qsB + pB);

  k_front<<<NB * NCHUNK, 256, 0, stream>>>(x, Wq, bq, Wk, Tpart, Kt_t, qsp);
  k_reduce<<<NB * 8, 256, 0, stream>>>(Tpart);
  k_pgemm<<<NB * 2, 256, 0, stream>>>(Tpart, qsp, Wv, bv, bk, P, h2);
  k_back<<<NB * 64, 256, 0, stream>>>(x, Kt_t, P, h2, gamma, out);
}

// Round 6
// 56.389 us; speedup vs baseline: 1.2487x; 1.0661x over previous
//
#include <hip/hip_runtime.h>

// SelfAttention2d, B=8 C=256 H=W=64 (N=4096), Ck=32, softmax dead code.
// out = gamma * (v q^T k) + x, reassociated:
//   Qt = X^T Wq^T + 1 bq^T      (N x 32, per-tile, LDS only)
//   Kt_t = X^T Wk^T             (N x 32, bf16, ws; bk folded into h)
//   T  = X Qt                   (256 x 32) n-chunked partials -> ws
//   qsum = Qt^T 1               (32)
//   P  = Wv T + bv qsum^T       (256 x 32), h = P bk  (j-split over 2 blocks)
//   out = gamma * (P Kt + h 1^T) + x   [back: pure streaming, no LDS]
// R6: weights staged to LDS as bf16 once per block (kills per-ks global
// loads + cvts in Qt/Kt loop); 512 front blocks (2/CU) with 64 Tpart chunks
// (ws ~268 MB per harness fill counters; 10.2 MB used).

constexpr int NB = 8;
constexpr int NC = 256;
constexpr int NK = 32;     // C/8
constexpr int NN = 4096;   // H*W
constexpr int NCHUNK = 64; // front n-chunks (64 n each)

typedef float  f32x4  __attribute__((ext_vector_type(4)));
typedef __bf16 bf16x4 __attribute__((ext_vector_type(4)));
typedef __bf16 bf16x8 __attribute__((ext_vector_type(8)));

__device__ __forceinline__ bf16x8 load_bf8(const float* __restrict__ p) {
  f32x4 a = *(const f32x4*)p;
  f32x4 b = *(const f32x4*)(p + 4);
  bf16x8 r;
  r[0] = (__bf16)a[0]; r[1] = (__bf16)a[1]; r[2] = (__bf16)a[2]; r[3] = (__bf16)a[3];
  r[4] = (__bf16)b[0]; r[5] = (__bf16)b[1]; r[6] = (__bf16)b[2]; r[7] = (__bf16)b[3];
  return r;
}

// ---------------- front: Qt/Kt for one 64-n subtile; T partial; qsum partial --
// grid = NB*64 (512 blocks, 2/CU), 256 threads (4 waves).
__global__ __launch_bounds__(256) void k_front(
    const float* __restrict__ x, const float* __restrict__ Wq,
    const float* __restrict__ bq, const float* __restrict__ Wk,
    __bf16* __restrict__ Tpart, __bf16* __restrict__ Kt_t,
    float* __restrict__ qsum_part) {
  __shared__ __bf16 ldsT[64][264];    // x-subtile transposed [n][c]
  __shared__ __bf16 ldsW[2][32][264]; // Wq, Wk bf16 [j][c]
  __shared__ __bf16 ldsQt[32][72];    // Q^T subtile [j][n]
  __shared__ __bf16 ldsKt[32][72];    // K^T subtile [j][n]
  __shared__ float  ldsQs[4][32];
  int bid = blockIdx.x;
  int b = bid >> 6, chunk = bid & 63;
  int nsub = chunk * 64;
  int t = threadIdx.x;
  int lane = t & 63, w = t >> 6, lr = lane & 15, lg = lane >> 4;
  const float* xb = x + (size_t)b * NC * NN;
  float bq0 = bq[lr], bq1 = bq[16 + lr];

  {  // weight stage: Wq/Wk f32[32][256] -> ldsW bf16, once per block
    int m = t >> 7, tid = t & 127;
    int j = tid >> 2, c0 = (tid & 3) * 64;
    const float* Ws = m ? Wk : Wq;
#pragma unroll
    for (int i = 0; i < 16; ++i) {
      f32x4 v = *(const f32x4*)(Ws + j * NC + c0 + i * 4);
      bf16x4 pk = {(__bf16)v[0], (__bf16)v[1], (__bf16)v[2], (__bf16)v[3]};
      *(bf16x4*)&ldsW[m][j][c0 + i * 4] = pk;
    }
  }
  {  // stage x[0:256][nsub:nsub+64] -> ldsT[n][c] bf16 (4x4 register transpose)
    int c0 = (t & 63) * 4, nq = (t >> 6) * 4;
#pragma unroll
    for (int p = 0; p < 4; ++p) {
      int n = p * 16 + nq;
      f32x4 v0 = *(const f32x4*)(xb + (size_t)(c0 + 0) * NN + nsub + n);
      f32x4 v1 = *(const f32x4*)(xb + (size_t)(c0 + 1) * NN + nsub + n);
      f32x4 v2 = *(const f32x4*)(xb + (size_t)(c0 + 2) * NN + nsub + n);
      f32x4 v3 = *(const f32x4*)(xb + (size_t)(c0 + 3) * NN + nsub + n);
#pragma unroll
      for (int i = 0; i < 4; ++i) {
        bf16x4 wv = {(__bf16)v0[i], (__bf16)v1[i], (__bf16)v2[i], (__bf16)v3[i]};
        *(bf16x4*)&ldsT[n + i][c0] = wv;
      }
    }
  }
  __syncthreads();
  // Qt(64x32) and Kt(64x32): all-LDS operands, 5x ds_read_b128 + 4 MFMA per ks
  f32x4 aq[2] = {}, ak[2] = {};
#pragma unroll
  for (int ks = 0; ks < 8; ++ks) {
    bf16x8 af = *(const bf16x8*)&ldsT[w * 16 + lr][ks * 32 + lg * 8];
    bf16x8 q0 = *(const bf16x8*)&ldsW[0][lr][ks * 32 + lg * 8];
    bf16x8 q1 = *(const bf16x8*)&ldsW[0][16 + lr][ks * 32 + lg * 8];
    bf16x8 k0 = *(const bf16x8*)&ldsW[1][lr][ks * 32 + lg * 8];
    bf16x8 k1 = *(const bf16x8*)&ldsW[1][16 + lr][ks * 32 + lg * 8];
    aq[0] = __builtin_amdgcn_mfma_f32_16x16x32_bf16(af, q0, aq[0], 0, 0, 0);
    aq[1] = __builtin_amdgcn_mfma_f32_16x16x32_bf16(af, q1, aq[1], 0, 0, 0);
    ak[0] = __builtin_amdgcn_mfma_f32_16x16x32_bf16(af, k0, ak[0], 0, 0, 0);
    ak[1] = __builtin_amdgcn_mfma_f32_16x16x32_bf16(af, k1, ak[1], 0, 0, 0);
  }
  float qs0, qs1;
#pragma unroll
  for (int r = 0; r < 4; ++r) { aq[0][r] += bq0; aq[1][r] += bq1; }
  qs0 = aq[0][0] + aq[0][1] + aq[0][2] + aq[0][3];
  qs1 = aq[1][0] + aq[1][1] + aq[1][2] + aq[1][3];
  {  // Qt / Kt -> LDS [j][n]
    bf16x4 p0 = {(__bf16)aq[0][0], (__bf16)aq[0][1], (__bf16)aq[0][2], (__bf16)aq[0][3]};
    bf16x4 p1 = {(__bf16)aq[1][0], (__bf16)aq[1][1], (__bf16)aq[1][2], (__bf16)aq[1][3]};
    *(bf16x4*)&ldsQt[lr][w * 16 + lg * 4] = p0;
    *(bf16x4*)&ldsQt[16 + lr][w * 16 + lg * 4] = p1;
    bf16x4 k0p = {(__bf16)ak[0][0], (__bf16)ak[0][1], (__bf16)ak[0][2], (__bf16)ak[0][3]};
    bf16x4 k1p = {(__bf16)ak[1][0], (__bf16)ak[1][1], (__bf16)ak[1][2], (__bf16)ak[1][3]};
    *(bf16x4*)&ldsKt[lr][w * 16 + lg * 4] = k0p;
    *(bf16x4*)&ldsKt[16 + lr][w * 16 + lg * 4] = k1p;
  }
  __syncthreads();
  {  // Kt coalesced store: thread t covers (nloc = t>>2, 8 j) -> 16 B store
    int nloc = t >> 2, j0 = (t & 3) * 8;
    bf16x8 pk;
#pragma unroll
    for (int i = 0; i < 8; ++i) pk[i] = ldsKt[j0 + i][nloc];
    *(bf16x8*)&Kt_t[((size_t)b * NN + nsub + nloc) * NK + j0] = pk;
  }
  // T(256x32) = X Qt : A = x rows from global (L1/L2-hot), B = ldsQt rows
  f32x4 accT[4][2] = {};
#pragma unroll
  for (int ks2 = 0; ks2 < 2; ++ks2) {
    bf16x8 bf0 = *(const bf16x8*)&ldsQt[lr][ks2 * 32 + lg * 8];
    bf16x8 bf1 = *(const bf16x8*)&ldsQt[16 + lr][ks2 * 32 + lg * 8];
#pragma unroll
    for (int mt = 0; mt < 4; ++mt) {
      int c = w * 64 + mt * 16 + lr;
      bf16x8 af = load_bf8(xb + (size_t)c * NN + nsub + ks2 * 32 + lg * 8);
      accT[mt][0] = __builtin_amdgcn_mfma_f32_16x16x32_bf16(af, bf0, accT[mt][0], 0, 0, 0);
      accT[mt][1] = __builtin_amdgcn_mfma_f32_16x16x32_bf16(af, bf1, accT[mt][1], 0, 0, 0);
    }
  }
  // qsum partial
  qs0 += __shfl_xor(qs0, 16); qs0 += __shfl_xor(qs0, 32);
  qs1 += __shfl_xor(qs1, 16); qs1 += __shfl_xor(qs1, 32);
  if (lane < 16) { ldsQs[w][lane] = qs0; ldsQs[w][16 + lane] = qs1; }
  __syncthreads();
  if (t < 32)
    qsum_part[(size_t)(chunk * NB + b) * NK + t] =
        ldsQs[0][t] + ldsQs[1][t] + ldsQs[2][t] + ldsQs[3][t];
  // Tpart[chunk][b][j][c] bf16 (D rows c are lane-consecutive -> bf16x4 packs)
  __bf16* Tp = Tpart + (size_t)(chunk * NB + b) * NC * NK;
#pragma unroll
  for (int mt = 0; mt < 4; ++mt)
#pragma unroll
    for (int jf = 0; jf < 2; ++jf) {
      bf16x4 pk = {(__bf16)accT[mt][jf][0], (__bf16)accT[mt][jf][1],
                   (__bf16)accT[mt][jf][2], (__bf16)accT[mt][jf][3]};
      *(bf16x4*)&Tp[(jf * 16 + lr) * NC + w * 64 + mt * 16 + lg * 4] = pk;
    }
}

// ---------------- reduce: T = sum_ch Tpart[ch], in-place into Tpart[ch=0] -----
// grid = NB*8 (64 blocks), 256 threads. Block (b, slice of 4 j-rows).
// Output region subset of own input region (ch=0), disjoint across blocks.
__global__ __launch_bounds__(256) void k_reduce(__bf16* __restrict__ Tpart) {
  int bid = blockIdx.x;
  int b = bid >> 3, slice = bid & 7;
  int t = threadIdx.x;
  int jo = t >> 6, c0 = (t & 63) * 4;
  const size_t chstride = (size_t)NB * NK * NC;
  size_t idx = ((size_t)b * NK + slice * 4 + jo) * NC + c0;
  float acc[4] = {};
#pragma unroll 8
  for (int ch = 0; ch < NCHUNK; ++ch) {
    bf16x4 v = *(const bf16x4*)&Tpart[ch * chstride + idx];
#pragma unroll
    for (int i = 0; i < 4; ++i) acc[i] += (float)v[i];
  }
  bf16x4 o = {(__bf16)acc[0], (__bf16)acc[1], (__bf16)acc[2], (__bf16)acc[3]};
  *(bf16x4*)&Tpart[idx] = o;
}

// ---------------- pgemm: P-half = Wv T_half + bv qsum^T ; h-half = P bk -------
// grid = NB*2 (j-split, 16 blocks), 256 threads
__global__ __launch_bounds__(256) void k_pgemm(
    const __bf16* __restrict__ T, const float* __restrict__ qsum_part,
    const float* __restrict__ Wv, const float* __restrict__ bv,
    const float* __restrict__ bk, __bf16* __restrict__ P,
    float* __restrict__ h2) {
  __shared__ __bf16 shTt[16][264];  // T^T half [j][c]
  __shared__ float shQsum[16];
  int bid = blockIdx.x;
  int b = bid >> 1, jg = bid & 1;
  int t = threadIdx.x;
  if (t < 16) {
    float s = 0.f;
#pragma unroll 8
    for (int ch = 0; ch < NCHUNK; ++ch)
      s += qsum_part[(size_t)(ch * NB + b) * NK + jg * 16 + t];
    shQsum[t] = s;
  }
  {  // copy reduced T half (16j x 256c bf16 = 8 KB) into LDS
    int j = t >> 5, c0 = (t & 31) * 8;
    bf16x8 v = *(const bf16x8*)&T[((size_t)b * NK + jg * 16 + j) * NC + c0];
    *(bf16x8*)&shTt[j][c0] = v;
  }
  __syncthreads();
  int lane = t & 63, w = t >> 6, lr = lane & 15, lg = lane >> 4;
  float bkj = bk[jg * 16 + lr];
  f32x4 accP[4] = {};
#pragma unroll
  for (int ks = 0; ks < 8; ++ks) {
    bf16x8 b0 = *(const bf16x8*)&shTt[lr][ks * 32 + lg * 8];
#pragma unroll
    for (int mt = 0; mt < 4; ++mt) {
      int c = w * 64 + mt * 16 + lr;
      bf16x8 af = load_bf8(Wv + (size_t)c * NC + ks * 32 + lg * 8);
      accP[mt] = __builtin_amdgcn_mfma_f32_16x16x32_bf16(af, b0, accP[mt], 0, 0, 0);
    }
  }
  float qs = shQsum[lr];
#pragma unroll
  for (int mt = 0; mt < 4; ++mt) {
    float hacc[4];
#pragma unroll
    for (int r = 0; r < 4; ++r) {
      int c = w * 64 + mt * 16 + lg * 4 + r;
      float val = accP[mt][r] + bv[c] * qs;
      P[((size_t)b * NC + c) * NK + jg * 16 + lr] = (__bf16)val;
      hacc[r] = val * bkj;
    }
#pragma unroll
    for (int r = 0; r < 4; ++r) {
      float v = hacc[r];
      v += __shfl_xor(v, 1); v += __shfl_xor(v, 2);
      v += __shfl_xor(v, 4); v += __shfl_xor(v, 8);
      if (lr == 0)
        h2[((size_t)b * 2 + jg) * NC + w * 64 + mt * 16 + lg * 4 + r] = v;
    }
  }
}

// ---------------- back: out = gamma*(P Kt + h 1^T) + x -----------------------
// D[n][c] orientation: A = Kt_t[n][j] (global, contiguous), B = P[c][j] rows.
// grid = NB*64 (n-tiles of 64), 256 threads (4 waves), NO LDS, NO syncs.
__global__ __launch_bounds__(256) void k_back(
    const float* __restrict__ x, const __bf16* __restrict__ Kt_t,
    const __bf16* __restrict__ P, const float* __restrict__ h2,
    const float* __restrict__ gamma, float* __restrict__ out) {
  int bid = blockIdx.x;
  int b = bid >> 6, n0 = (bid & 63) * 64;
  int t = threadIdx.x;
  int lane = t & 63, w = t >> 6, lr = lane & 15, lg = lane >> 4;

  bf16x8 af = *(const bf16x8*)&Kt_t[((size_t)b * NN + n0 + w * 16 + lr) * NK + lg * 8];
  const __bf16* Pb = P + (size_t)b * NC * NK;
  f32x4 acc[16];
#pragma unroll
  for (int ft = 0; ft < 16; ++ft) {
    bf16x8 bfr = *(const bf16x8*)&Pb[(size_t)(ft * 16 + lr) * NK + lg * 8];
    f32x4 z = {0.f, 0.f, 0.f, 0.f};
    acc[ft] = __builtin_amdgcn_mfma_f32_16x16x32_bf16(af, bfr, z, 0, 0, 0);
  }
  float g = gamma[0];
  const float* h0 = h2 + (size_t)b * 2 * NC;
#pragma unroll
  for (int ft = 0; ft < 16; ++ft) {
    int c = ft * 16 + lr;
    float hc = h0[c] + h0[NC + c];
    size_t idx = ((size_t)b * NC + c) * NN + n0 + w * 16 + lg * 4;
    f32x4 xv = *(const f32x4*)&x[idx];
    f32x4 o;
#pragma unroll
    for (int r = 0; r < 4; ++r) o[r] = g * (acc[ft][r] + hc) + xv[r];
    *(f32x4*)&out[idx] = o;
  }
}

extern "C" void kernel_launch(void* const* d_in, const int* in_sizes, int n_in,
                              void* d_out, int out_size, void* d_ws, size_t ws_size,
                              hipStream_t stream) {
  (void)in_sizes; (void)n_in; (void)out_size; (void)ws_size;
  const float* x     = (const float*)d_in[0];
  const float* Wk    = (const float*)d_in[1];
  const float* bk    = (const float*)d_in[2];
  const float* Wq    = (const float*)d_in[3];
  const float* bq    = (const float*)d_in[4];
  const float* Wv    = (const float*)d_in[5];
  const float* bv    = (const float*)d_in[6];
  const float* gamma = (const float*)d_in[7];
  float* out = (float*)d_out;

  char* wsb = (char*)d_ws;
  const size_t tpB = (size_t)NCHUNK * NB * NC * NK * 2;  // 8 MB
  const size_t ktB = (size_t)NB * NN * NK * 2;           // 2 MB
  const size_t qsB = (size_t)NCHUNK * NB * NK * 4;       // 64 KB
  const size_t pB  = (size_t)NB * NC * NK * 2;           // 128 KB
  __bf16* Tpart = (__bf16*)wsb;
  __bf16* Kt_t  = (__bf16*)(wsb + tpB);
  float*  qsp   = (float*)(wsb + tpB + ktB);
  __bf16* P     = (__bf16*)(wsb + tpB + ktB + qsB);
  float*  h2    = (float*)(wsb + tpB + ktB + qsB + pB);

  k_front<<<NB * NCHUNK, 256, 0, stream>>>(x, Wq, bq, Wk, Tpart, Kt_t, qsp);
  k_reduce<<<NB * 8, 256, 0, stream>>>(Tpart);
  k_pgemm<<<NB * 2, 256, 0, stream>>>(Tpart, qsp, Wv, bv, bk, P, h2);
  k_back<<<NB * 64, 256, 0, stream>>>(x, Kt_t, P, h2, gamma, out);
}

// Round 7
// 52.167 us; speedup vs baseline: 1.3497x; 1.0809x over previous
//
#include <hip/hip_runtime.h>

// SelfAttention2d, B=8 C=256 H=W=64 (N=4096), Ck=32, softmax dead code.
// out = gamma * (v q^T k) + x, reassociated:
//   Qt = X^T Wq^T + 1 bq^T      (N x 32, per-tile, LDS only)
//   Kt_t = X^T Wk^T             (N x 32, bf16, ws; bk folded into h)
//   T  = X Qt                   (256 x 32) n-chunked partials -> ws
//   qsum = Qt^T 1               (32)
//   P  = Wv T + bv qsum^T       (256 x 32), h = P bk  (j-split over 2 blocks)
//   out = gamma * (P Kt + h 1^T) + x   [back: pure streaming, no LDS]
// R7: front x-stage made fully coalesced (4-row x 256B segments) with an
// XOR-swizzled ldsT (el = n*264 + (c ^ (((n>>2)&7)<<3))) applied on BOTH
// write and read sides. Everything else identical to R6.

constexpr int NB = 8;
constexpr int NC = 256;
constexpr int NK = 32;     // C/8
constexpr int NN = 4096;   // H*W
constexpr int NCHUNK = 64; // front n-chunks (64 n each)

typedef float  f32x4  __attribute__((ext_vector_type(4)));
typedef __bf16 bf16x4 __attribute__((ext_vector_type(4)));
typedef __bf16 bf16x8 __attribute__((ext_vector_type(8)));

__device__ __forceinline__ bf16x8 load_bf8(const float* __restrict__ p) {
  f32x4 a = *(const f32x4*)p;
  f32x4 b = *(const f32x4*)(p + 4);
  bf16x8 r;
  r[0] = (__bf16)a[0]; r[1] = (__bf16)a[1]; r[2] = (__bf16)a[2]; r[3] = (__bf16)a[3];
  r[4] = (__bf16)b[0]; r[5] = (__bf16)b[1]; r[6] = (__bf16)b[2]; r[7] = (__bf16)b[3];
  return r;
}

// ---------------- front: Qt/Kt for one 64-n subtile; T partial; qsum partial --
// grid = NB*64 (512 blocks, 2/CU), 256 threads (4 waves).
__global__ __launch_bounds__(256) void k_front(
    const float* __restrict__ x, const float* __restrict__ Wq,
    const float* __restrict__ bq, const float* __restrict__ Wk,
    __bf16* __restrict__ Tpart, __bf16* __restrict__ Kt_t,
    float* __restrict__ qsum_part) {
  __shared__ __bf16 ldsT[64 * 264];   // x-subtile transposed [n][c], XOR-swizzled
  __shared__ __bf16 ldsW[2][32][264]; // Wq, Wk bf16 [j][c]
  __shared__ __bf16 ldsQt[32][72];    // Q^T subtile [j][n]
  __shared__ __bf16 ldsKt[32][72];    // K^T subtile [j][n]
  __shared__ float  ldsQs[4][32];
  int bid = blockIdx.x;
  int b = bid >> 6, chunk = bid & 63;
  int nsub = chunk * 64;
  int t = threadIdx.x;
  int lane = t & 63, w = t >> 6, lr = lane & 15, lg = lane >> 4;
  const float* xb = x + (size_t)b * NC * NN;
  float bq0 = bq[lr], bq1 = bq[16 + lr];

  {  // weight stage: Wq/Wk f32[32][256] -> ldsW bf16, once per block
    int m = t >> 7, tid = t & 127;
    int j = tid >> 2, c0 = (tid & 3) * 64;
    const float* Ws = m ? Wk : Wq;
#pragma unroll
    for (int i = 0; i < 16; ++i) {
      f32x4 v = *(const f32x4*)(Ws + j * NC + c0 + i * 4);
      bf16x4 pk = {(__bf16)v[0], (__bf16)v[1], (__bf16)v[2], (__bf16)v[3]};
      *(bf16x4*)&ldsW[m][j][c0 + i * 4] = pk;
    }
  }
  {  // stage x[0:256][nsub:nsub+64] -> ldsT swizzled, fully coalesced reads:
     // per instruction a wave reads 4 rows x 256 B contiguous segments.
    int cg = t >> 4, ng = t & 15;
    int n0 = ng * 4;
    int swzEl = (ng & 7) << 3;
#pragma unroll
    for (int r = 0; r < 4; ++r) {
      int c0 = r * 64 + cg * 4;
      const float* src = xb + (size_t)c0 * NN + nsub + n0;
      f32x4 L0 = *(const f32x4*)(src);
      f32x4 L1 = *(const f32x4*)(src + NN);
      f32x4 L2 = *(const f32x4*)(src + 2 * NN);
      f32x4 L3 = *(const f32x4*)(src + 3 * NN);
#pragma unroll
      for (int jj = 0; jj < 4; ++jj) {
        bf16x4 pk = {(__bf16)L0[jj], (__bf16)L1[jj], (__bf16)L2[jj], (__bf16)L3[jj]};
        *(bf16x4*)&ldsT[(n0 + jj) * 264 + (c0 ^ swzEl)] = pk;
      }
    }
  }
  __syncthreads();
  // Qt(64x32) and Kt(64x32): all-LDS operands; A-frag reads use the swizzle
  f32x4 aq[2] = {}, ak[2] = {};
  {
    int n = w * 16 + lr;
    int swzA = ((n >> 2) & 7) << 3;
    int rowA = n * 264;
#pragma unroll
    for (int ks = 0; ks < 8; ++ks) {
      bf16x8 af = *(const bf16x8*)&ldsT[rowA + ((ks * 32 + lg * 8) ^ swzA)];
      bf16x8 q0 = *(const bf16x8*)&ldsW[0][lr][ks * 32 + lg * 8];
      bf16x8 q1 = *(const bf16x8*)&ldsW[0][16 + lr][ks * 32 + lg * 8];
      bf16x8 k0 = *(const bf16x8*)&ldsW[1][lr][ks * 32 + lg * 8];
      bf16x8 k1 = *(const bf16x8*)&ldsW[1][16 + lr][ks * 32 + lg * 8];
      aq[0] = __builtin_amdgcn_mfma_f32_16x16x32_bf16(af, q0, aq[0], 0, 0, 0);
      aq[1] = __builtin_amdgcn_mfma_f32_16x16x32_bf16(af, q1, aq[1], 0, 0, 0);
      ak[0] = __builtin_amdgcn_mfma_f32_16x16x32_bf16(af, k0, ak[0], 0, 0, 0);
      ak[1] = __builtin_amdgcn_mfma_f32_16x16x32_bf16(af, k1, ak[1], 0, 0, 0);
    }
  }
  float qs0, qs1;
#pragma unroll
  for (int r = 0; r < 4; ++r) { aq[0][r] += bq0; aq[1][r] += bq1; }
  qs0 = aq[0][0] + aq[0][1] + aq[0][2] + aq[0][3];
  qs1 = aq[1][0] + aq[1][1] + aq[1][2] + aq[1][3];
  {  // Qt / Kt -> LDS [j][n]
    bf16x4 p0 = {(__bf16)aq[0][0], (__bf16)aq[0][1], (__bf16)aq[0][2], (__bf16)aq[0][3]};
    bf16x4 p1 = {(__bf16)aq[1][0], (__bf16)aq[1][1], (__bf16)aq[1][2], (__bf16)aq[1][3]};
    *(bf16x4*)&ldsQt[lr][w * 16 + lg * 4] = p0;
    *(bf16x4*)&ldsQt[16 + lr][w * 16 + lg * 4] = p1;
    bf16x4 k0p = {(__bf16)ak[0][0], (__bf16)ak[0][1], (__bf16)ak[0][2], (__bf16)ak[0][3]};
    bf16x4 k1p = {(__bf16)ak[1][0], (__bf16)ak[1][1], (__bf16)ak[1][2], (__bf16)ak[1][3]};
    *(bf16x4*)&ldsKt[lr][w * 16 + lg * 4] = k0p;
    *(bf16x4*)&ldsKt[16 + lr][w * 16 + lg * 4] = k1p;
  }
  __syncthreads();
  {  // Kt coalesced store: thread t covers (nloc = t>>2, 8 j) -> 16 B store
    int nloc = t >> 2, j0 = (t & 3) * 8;
    bf16x8 pk;
#pragma unroll
    for (int i = 0; i < 8; ++i) pk[i] = ldsKt[j0 + i][nloc];
    *(bf16x8*)&Kt_t[((size_t)b * NN + nsub + nloc) * NK + j0] = pk;
  }
  // T(256x32) = X Qt : A = x rows from global (L1/L2-hot), B = ldsQt rows
  f32x4 accT[4][2] = {};
#pragma unroll
  for (int ks2 = 0; ks2 < 2; ++ks2) {
    bf16x8 bf0 = *(const bf16x8*)&ldsQt[lr][ks2 * 32 + lg * 8];
    bf16x8 bf1 = *(const bf16x8*)&ldsQt[16 + lr][ks2 * 32 + lg * 8];
#pragma unroll
    for (int mt = 0; mt < 4; ++mt) {
      int c = w * 64 + mt * 16 + lr;
      bf16x8 af = load_bf8(xb + (size_t)c * NN + nsub + ks2 * 32 + lg * 8);
      accT[mt][0] = __builtin_amdgcn_mfma_f32_16x16x32_bf16(af, bf0, accT[mt][0], 0, 0, 0);
      accT[mt][1] = __builtin_amdgcn_mfma_f32_16x16x32_bf16(af, bf1, accT[mt][1], 0, 0, 0);
    }
  }
  // qsum partial
  qs0 += __shfl_xor(qs0, 16); qs0 += __shfl_xor(qs0, 32);
  qs1 += __shfl_xor(qs1, 16); qs1 += __shfl_xor(qs1, 32);
  if (lane < 16) { ldsQs[w][lane] = qs0; ldsQs[w][16 + lane] = qs1; }
  __syncthreads();
  if (t < 32)
    qsum_part[(size_t)(chunk * NB + b) * NK + t] =
        ldsQs[0][t] + ldsQs[1][t] + ldsQs[2][t] + ldsQs[3][t];
  // Tpart[chunk][b][j][c] bf16 (D rows c are lane-consecutive -> bf16x4 packs)
  __bf16* Tp = Tpart + (size_t)(chunk * NB + b) * NC * NK;
#pragma unroll
  for (int mt = 0; mt < 4; ++mt)
#pragma unroll
    for (int jf = 0; jf < 2; ++jf) {
      bf16x4 pk = {(__bf16)accT[mt][jf][0], (__bf16)accT[mt][jf][1],
                   (__bf16)accT[mt][jf][2], (__bf16)accT[mt][jf][3]};
      *(bf16x4*)&Tp[(jf * 16 + lr) * NC + w * 64 + mt * 16 + lg * 4] = pk;
    }
}

// ---------------- reduce: T = sum_ch Tpart[ch], in-place into Tpart[ch=0] -----
// grid = NB*8 (64 blocks), 256 threads. Block (b, slice of 4 j-rows).
// Output region subset of own input region (ch=0), disjoint across blocks.
__global__ __launch_bounds__(256) void k_reduce(__bf16* __restrict__ Tpart) {
  int bid = blockIdx.x;
  int b = bid >> 3, slice = bid & 7;
  int t = threadIdx.x;
  int jo = t >> 6, c0 = (t & 63) * 4;
  const size_t chstride = (size_t)NB * NK * NC;
  size_t idx = ((size_t)b * NK + slice * 4 + jo) * NC + c0;
  float acc[4] = {};
#pragma unroll 8
  for (int ch = 0; ch < NCHUNK; ++ch) {
    bf16x4 v = *(const bf16x4*)&Tpart[ch * chstride + idx];
#pragma unroll
    for (int i = 0; i < 4; ++i) acc[i] += (float)v[i];
  }
  bf16x4 o = {(__bf16)acc[0], (__bf16)acc[1], (__bf16)acc[2], (__bf16)acc[3]};
  *(bf16x4*)&Tpart[idx] = o;
}

// ---------------- pgemm: P-half = Wv T_half + bv qsum^T ; h-half = P bk -------
// grid = NB*2 (j-split, 16 blocks), 256 threads
__global__ __launch_bounds__(256) void k_pgemm(
    const __bf16* __restrict__ T, const float* __restrict__ qsum_part,
    const float* __restrict__ Wv, const float* __restrict__ bv,
    const float* __restrict__ bk, __bf16* __restrict__ P,
    float* __restrict__ h2) {
  __shared__ __bf16 shTt[16][264];  // T^T half [j][c]
  __shared__ float shQsum[16];
  int bid = blockIdx.x;
  int b = bid >> 1, jg = bid & 1;
  int t = threadIdx.x;
  if (t < 16) {
    float s = 0.f;
#pragma unroll 8
    for (int ch = 0; ch < NCHUNK; ++ch)
      s += qsum_part[(size_t)(ch * NB + b) * NK + jg * 16 + t];
    shQsum[t] = s;
  }
  {  // copy reduced T half (16j x 256c bf16 = 8 KB) into LDS
    int j = t >> 5, c0 = (t & 31) * 8;
    bf16x8 v = *(const bf16x8*)&T[((size_t)b * NK + jg * 16 + j) * NC + c0];
    *(bf16x8*)&shTt[j][c0] = v;
  }
  __syncthreads();
  int lane = t & 63, w = t >> 6, lr = lane & 15, lg = lane >> 4;
  float bkj = bk[jg * 16 + lr];
  f32x4 accP[4] = {};
#pragma unroll
  for (int ks = 0; ks < 8; ++ks) {
    bf16x8 b0 = *(const bf16x8*)&shTt[lr][ks * 32 + lg * 8];
#pragma unroll
    for (int mt = 0; mt < 4; ++mt) {
      int c = w * 64 + mt * 16 + lr;
      bf16x8 af = load_bf8(Wv + (size_t)c * NC + ks * 32 + lg * 8);
      accP[mt] = __builtin_amdgcn_mfma_f32_16x16x32_bf16(af, b0, accP[mt], 0, 0, 0);
    }
  }
  float qs = shQsum[lr];
#pragma unroll
  for (int mt = 0; mt < 4; ++mt) {
    float hacc[4];
#pragma unroll
    for (int r = 0; r < 4; ++r) {
      int c = w * 64 + mt * 16 + lg * 4 + r;
      float val = accP[mt][r] + bv[c] * qs;
      P[((size_t)b * NC + c) * NK + jg * 16 + lr] = (__bf16)val;
      hacc[r] = val * bkj;
    }
#pragma unroll
    for (int r = 0; r < 4; ++r) {
      float v = hacc[r];
      v += __shfl_xor(v, 1); v += __shfl_xor(v, 2);
      v += __shfl_xor(v, 4); v += __shfl_xor(v, 8);
      if (lr == 0)
        h2[((size_t)b * 2 + jg) * NC + w * 64 + mt * 16 + lg * 4 + r] = v;
    }
  }
}

// ---------------- back: out = gamma*(P Kt + h 1^T) + x -----------------------
// D[n][c] orientation: A = Kt_t[n][j] (global, contiguous), B = P[c][j] rows.
// grid = NB*64 (n-tiles of 64), 256 threads (4 waves), NO LDS, NO syncs.
__global__ __launch_bounds__(256) void k_back(
    const float* __restrict__ x, const __bf16* __restrict__ Kt_t,
    const __bf16* __restrict__ P, const float* __restrict__ h2,
    const float* __restrict__ gamma, float* __restrict__ out) {
  int bid = blockIdx.x;
  int b = bid >> 6, n0 = (bid & 63) * 64;
  int t = threadIdx.x;
  int lane = t & 63, w = t >> 6, lr = lane & 15, lg = lane >> 4;

  bf16x8 af = *(const bf16x8*)&Kt_t[((size_t)b * NN + n0 + w * 16 + lr) * NK + lg * 8];
  const __bf16* Pb = P + (size_t)b * NC * NK;
  f32x4 acc[16];
#pragma unroll
  for (int ft = 0; ft < 16; ++ft) {
    bf16x8 bfr = *(const bf16x8*)&Pb[(size_t)(ft * 16 + lr) * NK + lg * 8];
    f32x4 z = {0.f, 0.f, 0.f, 0.f};
    acc[ft] = __builtin_amdgcn_mfma_f32_16x16x32_bf16(af, bfr, z, 0, 0, 0);
  }
  float g = gamma[0];
  const float* h0 = h2 + (size_t)b * 2 * NC;
#pragma unroll
  for (int ft = 0; ft < 16; ++ft) {
    int c = ft * 16 + lr;
    float hc = h0[c] + h0[NC + c];
    size_t idx = ((size_t)b * NC + c) * NN + n0 + w * 16 + lg * 4;
    f32x4 xv = *(const f32x4*)&x[idx];
    f32x4 o;
#pragma unroll
    for (int r = 0; r < 4; ++r) o[r] = g * (acc[ft][r] + hc) + xv[r];
    *(f32x4*)&out[idx] = o;
  }
}

extern "C" void kernel_launch(void* const* d_in, const int* in_sizes, int n_in,
                              void* d_out, int out_size, void* d_ws, size_t ws_size,
                              hipStream_t stream) {
  (void)in_sizes; (void)n_in; (void)out_size; (void)ws_size;
  const float* x     = (const float*)d_in[0];
  const float* Wk    = (const float*)d_in[1];
  const float* bk    = (const float*)d_in[2];
  const float* Wq    = (const float*)d_in[3];
  const float* bq    = (const float*)d_in[4];
  const float* Wv    = (const float*)d_in[5];
  const float* bv    = (const float*)d_in[6];
  const float* gamma = (const float*)d_in[7];
  float* out = (float*)d_out;

  char* wsb = (char*)d_ws;
  const size_t tpB = (size_t)NCHUNK * NB * NC * NK * 2;  // 8 MB
  const size_t ktB = (size_t)NB * NN * NK * 2;           // 2 MB
  const size_t qsB = (size_t)NCHUNK * NB * NK * 4;       // 64 KB
  const size_t pB  = (size_t)NB * NC * NK * 2;           // 128 KB
  __bf16* Tpart = (__bf16*)wsb;
  __bf16* Kt_t  = (__bf16*)(wsb + tpB);
  float*  qsp   = (float*)(wsb + tpB + ktB);
  __bf16* P     = (__bf16*)(wsb + tpB + ktB + qsB);
  float*  h2    = (float*)(wsb + tpB + ktB + qsB + pB);

  k_front<<<NB * NCHUNK, 256, 0, stream>>>(x, Wq, bq, Wk, Tpart, Kt_t, qsp);
  k_reduce<<<NB * 8, 256, 0, stream>>>(Tpart);
  k_pgemm<<<NB * 2, 256, 0, stream>>>(Tpart, qsp, Wv, bv, bk, P, h2);
  k_back<<<NB * 64, 256, 0, stream>>>(x, Kt_t, P, h2, gamma, out);
}